// Round 1
// baseline (232.449 us; speedup 1.0000x reference)
//
#include <hip/hip_runtime.h>
#include <math.h>

// DifferentiableRAM: out[b,c,n,m] = gamma[b] * sum_w ( sum_h Fy[b,n,h]*x[b,c,h,w] ) * Fx[b,m,w]
// B=32, C=3, H=W=512, N=256.
// ws layout (fp32): Fx [32,256,512] | Fy [32,256,512] | Fyx [32,3,256,512]  => 84 MB

namespace {

constexpr int Bn = 32;
constexpr int Cc = 3;
constexpr int HW = 512;   // H == W == 512
constexpr int Nn = 256;
constexpr float SMALLF = 1e-4f;

// ---------------- Kernel 1: Gaussian filterbanks -------------------------
// One wave (64 lanes) per (which, b, n) row of 512 elements; 4 waves/block.
__global__ __launch_bounds__(256) void fb_kernel(const float* __restrict__ p,
                                                 float* __restrict__ Fx,
                                                 float* __restrict__ Fy) {
    const int wid  = threadIdx.x >> 6;
    const int lane = threadIdx.x & 63;
    const int rid  = blockIdx.x * 4 + wid;        // 0 .. 16383
    const int which = rid >> 13;                  // 0 -> Fx, 1 -> Fy  (8192 rows each)
    const int r = rid & 8191;
    const int b = r >> 8;
    const int n = r & 255;

    const float* pb = p + b * 5;
    const float sigma2 = expf(pb[2]);
    const float delta  = expf(pb[3]) * (511.0f / 255.0f);
    const float g = (which == 0) ? (HW * (pb[0] + 1.0f) * 0.5f)
                                 : (HW * (pb[1] + 1.0f) * 0.5f);
    const float mu = g + delta * ((float)n - 128.5f);   // n - N/2 - 0.5
    const float inv2s = 0.5f / sigma2;

    float f[8];
    float sum = 0.0f;
#pragma unroll
    for (int q = 0; q < 8; ++q) {
        float a = (float)(q * 64 + lane);
        float d = a - mu;
        f[q] = expf(-d * d * inv2s);
        sum += f[q];
    }
#pragma unroll
    for (int s = 1; s < 64; s <<= 1) sum += __shfl_xor(sum, s, 64);
    const float inv = 1.0f / (sum + SMALLF);

    float* dst = ((which == 0) ? Fx : Fy) + ((size_t)(b * Nn + n)) * HW;
#pragma unroll
    for (int q = 0; q < 8; ++q) dst[q * 64 + lane] = f[q] * inv;
}

// ---------------- Kernel 2: Fyx[bc][n][w] = Fy[b] @ x[bc] -----------------
// 64x64 tile per block, 256 threads, 4x4 micro-tile, K-step 16.
__global__ __launch_bounds__(256) void gemm1_kernel(const float* __restrict__ Fy,
                                                    const float* __restrict__ x,
                                                    float* __restrict__ Fyx) {
    __shared__ float As[16][68];   // [k][m] (transposed A tile; 68 keeps float4 align)
    __shared__ float Bs[16][64];   // [k][w]

    const int t  = threadIdx.x;
    const int tx = t & 15;
    const int ty = t >> 4;
    const int w0 = blockIdx.x * 64;
    const int n0 = blockIdx.y * 64;
    const int bc = blockIdx.z;
    const int b  = bc / 3;

    const float* Ag = Fy + (size_t)b * Nn * HW + (size_t)n0 * HW;   // [64 n][512 h]
    const float* Bg = x + (size_t)bc * HW * HW;                     // [512 h][512 w]

    const int am  = t >> 2;          // 0..63 row of A tile
    const int akq = (t & 3) << 2;    // 0,4,8,12 k-quad
    const int bk  = t >> 4;          // 0..15 row of B tile
    const int bwq = (t & 15) << 2;   // col quad

    float acc[4][4] = {};

    for (int k0 = 0; k0 < HW; k0 += 16) {
        const float4 av = *(const float4*)(Ag + (size_t)am * HW + k0 + akq);
        const float4 bv = *(const float4*)(Bg + (size_t)(k0 + bk) * HW + w0 + bwq);
        __syncthreads();
        As[akq + 0][am] = av.x;
        As[akq + 1][am] = av.y;
        As[akq + 2][am] = av.z;
        As[akq + 3][am] = av.w;
        *(float4*)&Bs[bk][bwq] = bv;
        __syncthreads();
#pragma unroll
        for (int kk = 0; kk < 16; ++kk) {
            const float4 a  = *(const float4*)&As[kk][ty * 4];
            const float4 bb = *(const float4*)&Bs[kk][tx * 4];
            acc[0][0] += a.x * bb.x; acc[0][1] += a.x * bb.y; acc[0][2] += a.x * bb.z; acc[0][3] += a.x * bb.w;
            acc[1][0] += a.y * bb.x; acc[1][1] += a.y * bb.y; acc[1][2] += a.y * bb.z; acc[1][3] += a.y * bb.w;
            acc[2][0] += a.z * bb.x; acc[2][1] += a.z * bb.y; acc[2][2] += a.z * bb.z; acc[2][3] += a.z * bb.w;
            acc[3][0] += a.w * bb.x; acc[3][1] += a.w * bb.y; acc[3][2] += a.w * bb.z; acc[3][3] += a.w * bb.w;
        }
    }

    float* Cg = Fyx + (size_t)bc * Nn * HW + (size_t)n0 * HW + w0;
#pragma unroll
    for (int i = 0; i < 4; ++i) {
        float4 v = make_float4(acc[i][0], acc[i][1], acc[i][2], acc[i][3]);
        *(float4*)(Cg + (size_t)(ty * 4 + i) * HW + tx * 4) = v;
    }
}

// ---------------- Kernel 3: out[bc][n][m] = gamma * Fyx[bc] @ Fx[b]^T -----
__global__ __launch_bounds__(256) void gemm2_kernel(const float* __restrict__ Fyx,
                                                    const float* __restrict__ Fxm,
                                                    const float* __restrict__ p,
                                                    float* __restrict__ out) {
    __shared__ float As[16][68];   // [k][n]
    __shared__ float Bs[16][68];   // [k][m]

    const int t  = threadIdx.x;
    const int tx = t & 15;
    const int ty = t >> 4;
    const int m0 = blockIdx.x * 64;
    const int n0 = blockIdx.y * 64;
    const int bc = blockIdx.z;
    const int b  = bc / 3;

    const float* Ag = Fyx + (size_t)bc * Nn * HW + (size_t)n0 * HW;  // [64 n][512 w]
    const float* Bg = Fxm + (size_t)b * Nn * HW + (size_t)m0 * HW;   // [64 m][512 w]
    const float gamma = expf(p[b * 5 + 4]);

    const int am  = t >> 2;
    const int akq = (t & 3) << 2;

    float acc[4][4] = {};

    for (int k0 = 0; k0 < HW; k0 += 16) {
        const float4 av = *(const float4*)(Ag + (size_t)am * HW + k0 + akq);
        const float4 bv = *(const float4*)(Bg + (size_t)am * HW + k0 + akq);
        __syncthreads();
        As[akq + 0][am] = av.x;
        As[akq + 1][am] = av.y;
        As[akq + 2][am] = av.z;
        As[akq + 3][am] = av.w;
        Bs[akq + 0][am] = bv.x;
        Bs[akq + 1][am] = bv.y;
        Bs[akq + 2][am] = bv.z;
        Bs[akq + 3][am] = bv.w;
        __syncthreads();
#pragma unroll
        for (int kk = 0; kk < 16; ++kk) {
            const float4 a  = *(const float4*)&As[kk][ty * 4];
            const float4 bb = *(const float4*)&Bs[kk][tx * 4];
            acc[0][0] += a.x * bb.x; acc[0][1] += a.x * bb.y; acc[0][2] += a.x * bb.z; acc[0][3] += a.x * bb.w;
            acc[1][0] += a.y * bb.x; acc[1][1] += a.y * bb.y; acc[1][2] += a.y * bb.z; acc[1][3] += a.y * bb.w;
            acc[2][0] += a.z * bb.x; acc[2][1] += a.z * bb.y; acc[2][2] += a.z * bb.z; acc[2][3] += a.z * bb.w;
            acc[3][0] += a.w * bb.x; acc[3][1] += a.w * bb.y; acc[3][2] += a.w * bb.z; acc[3][3] += a.w * bb.w;
        }
    }

    float* Cg = out + (size_t)bc * Nn * Nn + (size_t)n0 * Nn + m0;
#pragma unroll
    for (int i = 0; i < 4; ++i) {
        float4 v = make_float4(gamma * acc[i][0], gamma * acc[i][1],
                               gamma * acc[i][2], gamma * acc[i][3]);
        *(float4*)(Cg + (size_t)(ty * 4 + i) * Nn + tx * 4) = v;
    }
}

} // anonymous namespace

extern "C" void kernel_launch(void* const* d_in, const int* in_sizes, int n_in,
                              void* d_out, int out_size, void* d_ws, size_t ws_size,
                              hipStream_t stream) {
    const float* x = (const float*)d_in[0];   // [32,3,512,512]
    const float* p = (const float*)d_in[1];   // [32,5]
    float* out = (float*)d_out;               // [32,3,256,256]

    float* Fx  = (float*)d_ws;                         // 32*256*512
    float* Fy  = Fx + (size_t)Bn * Nn * HW;            // 32*256*512
    float* Fyx = Fy + (size_t)Bn * Nn * HW;            // 32*3*256*512

    hipLaunchKernelGGL(fb_kernel, dim3(4096), dim3(256), 0, stream, p, Fx, Fy);
    hipLaunchKernelGGL(gemm1_kernel, dim3(8, 4, Bn * Cc), dim3(256), 0, stream, Fy, x, Fyx);
    hipLaunchKernelGGL(gemm2_kernel, dim3(4, 4, Bn * Cc), dim3(256), 0, stream, Fyx, Fx, p, out);
}

// Round 4
// 86.074 us; speedup vs baseline: 2.7006x; 2.7006x over previous
//
#include <hip/hip_runtime.h>
#include <math.h>

// DifferentiableRAM: out[b,c,n,m] = gamma[b] * sum_w ( sum_h Fy[b,n,h]*x[b,c,h,w] ) * Fx[b,m,w]
// B=32, C=3, H=W=512, N=256.
// Pipeline: fb (p -> Fx_b, Fy_b bf16)  ->  xpose (x f32 -> xT bf16 [bc][w][h])
//           -> gemm1 MFMA (Fyx_b[bc][n][w] bf16 = Fy_b @ xT^T-form)
//           -> gemm2 MFMA (out f32 = gamma * Fyx_b @ Fx_b^T)
// ws: Fx_b 8MB | Fy_b 8MB | xT 50.3MB | Fyx_b 25.2MB  => 92.3 MB

namespace {

typedef __attribute__((ext_vector_type(8))) short v8s;    // 8 bf16 (MFMA A/B frag)
typedef __attribute__((ext_vector_type(4))) float f32x4;  // MFMA C/D frag

constexpr int Bn = 32;
constexpr int Cc = 3;
constexpr int HW = 512;
constexpr int Nn = 256;
constexpr float SMALLF = 1e-4f;

__device__ inline unsigned short f2bf(float f) {
    union { float f; unsigned u; } v; v.f = f;
    unsigned r = v.u + 0x7FFF + ((v.u >> 16) & 1);   // RNE
    return (unsigned short)(r >> 16);
}

// ---------------- Kernel 1: Gaussian filterbanks (bf16 out) ---------------
__global__ __launch_bounds__(256) void fb_kernel(const float* __restrict__ p,
                                                 unsigned short* __restrict__ Fx,
                                                 unsigned short* __restrict__ Fy) {
    const int wid  = threadIdx.x >> 6;
    const int lane = threadIdx.x & 63;
    const int rid  = blockIdx.x * 4 + wid;        // 0..16383
    const int which = rid >> 13;
    const int r = rid & 8191;
    const int b = r >> 8;
    const int n = r & 255;

    const float* pb = p + b * 5;
    const float sigma2 = expf(pb[2]);
    const float delta  = expf(pb[3]) * (511.0f / 255.0f);
    const float g = (which == 0) ? (HW * (pb[0] + 1.0f) * 0.5f)
                                 : (HW * (pb[1] + 1.0f) * 0.5f);
    const float mu = g + delta * ((float)n - 128.5f);
    const float inv2s = 0.5f / sigma2;

    float f[8];
    float sum = 0.0f;
#pragma unroll
    for (int q = 0; q < 8; ++q) {
        float a = (float)(q * 64 + lane);
        float d = a - mu;
        f[q] = expf(-d * d * inv2s);
        sum += f[q];
    }
#pragma unroll
    for (int s = 1; s < 64; s <<= 1) sum += __shfl_xor(sum, s, 64);
    const float inv = 1.0f / (sum + SMALLF);

    unsigned short* dst = ((which == 0) ? Fx : Fy) + ((size_t)(b * Nn + n)) * HW;
#pragma unroll
    for (int q = 0; q < 8; ++q) dst[q * 64 + lane] = f2bf(f[q] * inv);
}

// ---------------- Kernel 2: transpose + bf16 convert ----------------------
// xT[bc][w][h] (bf16) = x[bc][h][w] (f32).  64x64 tiles via LDS.
__global__ __launch_bounds__(256) void xpose_kernel(const float* __restrict__ x,
                                                    unsigned short* __restrict__ xT) {
    __shared__ float Ls[64][68];
    const int bc = blockIdx.z;
    const int w0 = blockIdx.x * 64;
    const int h0 = blockIdx.y * 64;
    const int t = threadIdx.x;

    const float* src = x + (size_t)bc * HW * HW;
    const int col4 = (t & 15) * 4;
    const int rb = t >> 4;
#pragma unroll
    for (int r = 0; r < 4; ++r) {
        int row = r * 16 + rb;
        *(float4*)&Ls[row][col4] = *(const float4*)(src + (size_t)(h0 + row) * HW + w0 + col4);
    }
    __syncthreads();

    unsigned short* dst = xT + (size_t)bc * HW * HW;
    const int wl = t & 63;
    const int hb = t >> 6;
#pragma unroll
    for (int r = 0; r < 2; ++r) {
        int hoct = hb + 4 * r;   // 0..7
        unsigned short v[8];
#pragma unroll
        for (int i = 0; i < 8; ++i) v[i] = f2bf(Ls[hoct * 8 + i][wl]);
        *(v8s*)(dst + (size_t)(w0 + wl) * HW + h0 + hoct * 8) = *(const v8s*)v;
    }
}

// ---------------- MFMA GEMM common -----------------------------------------
// Stage 128 rows x 64 k (bf16) from row-major src into swizzled linear LDS tile.
// byte(row,kbyte) = row*128 + (kbyte ^ ((row&7)<<4)).
__device__ inline void stage_tile(const unsigned short* __restrict__ src, int k0,
                                  unsigned short* __restrict__ lds, int t) {
    const int oct = t & 7;
    const int rowb = t >> 3;
#pragma unroll
    for (int r = 0; r < 4; ++r) {
        int row = rowb + 32 * r;
        v8s v = *(const v8s*)(src + (size_t)row * HW + k0 + oct * 8);
        int byte = row * 128 + ((oct * 16) ^ ((row & 7) << 4));
        *(v8s*)((char*)lds + byte) = v;
    }
}

__device__ inline v8s frag_read(const unsigned short* __restrict__ lds, int row, int kk, int lk) {
    int byte = row * 128 + (((kk * 64) + lk * 16) ^ ((row & 7) << 4));
    return *(const v8s*)((const char*)lds + byte);
}

// gemm1: Fyx_b[bc][n][w] = Fy_b[b] (256x512) @ x[bc] via xT rows (both k-contig).
__global__ __launch_bounds__(256) void gemm1_kernel(const unsigned short* __restrict__ Fy_b,
                                                    const unsigned short* __restrict__ xT,
                                                    unsigned short* __restrict__ Fyx_b) {
    __shared__ unsigned short As[128 * 64];
    __shared__ unsigned short Bs[128 * 64];
    const int t = threadIdx.x;
    const int bc = blockIdx.z, b = bc / 3;
    const int w0 = blockIdx.x * 128;
    const int n0 = blockIdx.y * 128;

    const unsigned short* Ag = Fy_b + (size_t)b * Nn * HW + (size_t)n0 * HW;
    const unsigned short* Bg = xT + (size_t)bc * HW * HW + (size_t)w0 * HW;

    const int wid = t >> 6, lane = t & 63, lr = lane & 15, lk = lane >> 4;
    const int wm = (wid >> 1) * 64, wn = (wid & 1) * 64;

    f32x4 acc[4][4];
#pragma unroll
    for (int i = 0; i < 4; ++i)
#pragma unroll
        for (int j = 0; j < 4; ++j) acc[i][j] = (f32x4){0.f, 0.f, 0.f, 0.f};

    for (int k0 = 0; k0 < HW; k0 += 64) {
        __syncthreads();
        stage_tile(Ag, k0, As, t);
        stage_tile(Bg, k0, Bs, t);
        __syncthreads();
#pragma unroll
        for (int kk = 0; kk < 2; ++kk) {
            v8s af[4], bf[4];
#pragma unroll
            for (int mi = 0; mi < 4; ++mi) af[mi] = frag_read(As, wm + mi * 16 + lr, kk, lk);
#pragma unroll
            for (int ni = 0; ni < 4; ++ni) bf[ni] = frag_read(Bs, wn + ni * 16 + lr, kk, lk);
#pragma unroll
            for (int mi = 0; mi < 4; ++mi)
#pragma unroll
                for (int ni = 0; ni < 4; ++ni)
                    acc[mi][ni] = __builtin_amdgcn_mfma_f32_16x16x32_bf16(af[mi], bf[ni], acc[mi][ni], 0, 0, 0);
        }
    }

    unsigned short* Cg = Fyx_b + (size_t)bc * Nn * HW + (size_t)(n0 + wm) * HW + (w0 + wn);
#pragma unroll
    for (int mi = 0; mi < 4; ++mi)
#pragma unroll
        for (int r = 0; r < 4; ++r) {
            int row = mi * 16 + lk * 4 + r;
#pragma unroll
            for (int ni = 0; ni < 4; ++ni)
                Cg[(size_t)row * HW + ni * 16 + lr] = f2bf(acc[mi][ni][r]);
        }
}

// gemm2: out[bc][n][m] = gamma * Fyx_b[bc] (256x512) @ Fx_b[b]^T (512x256)
__global__ __launch_bounds__(256) void gemm2_kernel(const unsigned short* __restrict__ Fyx_b,
                                                    const unsigned short* __restrict__ Fx_b,
                                                    const float* __restrict__ p,
                                                    float* __restrict__ out) {
    __shared__ unsigned short As[128 * 64];
    __shared__ unsigned short Bs[128 * 64];
    const int t = threadIdx.x;
    const int bc = blockIdx.z, b = bc / 3;
    const int m0 = blockIdx.x * 128;
    const int n0 = blockIdx.y * 128;

    const unsigned short* Ag = Fyx_b + (size_t)bc * Nn * HW + (size_t)n0 * HW;
    const unsigned short* Bg = Fx_b + (size_t)b * Nn * HW + (size_t)m0 * HW;
    const float gamma = expf(p[b * 5 + 4]);

    const int wid = t >> 6, lane = t & 63, lr = lane & 15, lk = lane >> 4;
    const int wm = (wid >> 1) * 64, wn = (wid & 1) * 64;

    f32x4 acc[4][4];
#pragma unroll
    for (int i = 0; i < 4; ++i)
#pragma unroll
        for (int j = 0; j < 4; ++j) acc[i][j] = (f32x4){0.f, 0.f, 0.f, 0.f};

    for (int k0 = 0; k0 < HW; k0 += 64) {
        __syncthreads();
        stage_tile(Ag, k0, As, t);
        stage_tile(Bg, k0, Bs, t);
        __syncthreads();
#pragma unroll
        for (int kk = 0; kk < 2; ++kk) {
            v8s af[4], bf[4];
#pragma unroll
            for (int mi = 0; mi < 4; ++mi) af[mi] = frag_read(As, wm + mi * 16 + lr, kk, lk);
#pragma unroll
            for (int ni = 0; ni < 4; ++ni) bf[ni] = frag_read(Bs, wn + ni * 16 + lr, kk, lk);
#pragma unroll
            for (int mi = 0; mi < 4; ++mi)
#pragma unroll
                for (int ni = 0; ni < 4; ++ni)
                    acc[mi][ni] = __builtin_amdgcn_mfma_f32_16x16x32_bf16(af[mi], bf[ni], acc[mi][ni], 0, 0, 0);
        }
    }

    float* Cg = out + (size_t)bc * Nn * Nn + (size_t)(n0 + wm) * Nn + (m0 + wn);
#pragma unroll
    for (int mi = 0; mi < 4; ++mi)
#pragma unroll
        for (int r = 0; r < 4; ++r) {
            int row = mi * 16 + lk * 4 + r;
#pragma unroll
            for (int ni = 0; ni < 4; ++ni)
                Cg[(size_t)row * Nn + ni * 16 + lr] = gamma * acc[mi][ni][r];
        }
}

} // anonymous namespace

extern "C" void kernel_launch(void* const* d_in, const int* in_sizes, int n_in,
                              void* d_out, int out_size, void* d_ws, size_t ws_size,
                              hipStream_t stream) {
    const float* x = (const float*)d_in[0];   // [32,3,512,512]
    const float* p = (const float*)d_in[1];   // [32,5]
    float* out = (float*)d_out;               // [32,3,256,256] f32

    char* ws = (char*)d_ws;
    unsigned short* Fx_b  = (unsigned short*)ws;                               // 32*256*512
    unsigned short* Fy_b  = Fx_b + (size_t)Bn * Nn * HW;                       // 32*256*512
    unsigned short* xT    = Fy_b + (size_t)Bn * Nn * HW;                       // 96*512*512
    unsigned short* Fyx_b = xT + (size_t)Bn * Cc * HW * HW;                    // 96*256*512

    hipLaunchKernelGGL(fb_kernel, dim3(4096), dim3(256), 0, stream, p, Fx_b, Fy_b);
    hipLaunchKernelGGL(xpose_kernel, dim3(8, 8, Bn * Cc), dim3(256), 0, stream, x, xT);
    hipLaunchKernelGGL(gemm1_kernel, dim3(4, 2, Bn * Cc), dim3(256), 0, stream, Fy_b, xT, Fyx_b);
    hipLaunchKernelGGL(gemm2_kernel, dim3(2, 2, Bn * Cc), dim3(256), 0, stream, Fyx_b, Fx_b, p, out);
}

// Round 5
// 70.792 us; speedup vs baseline: 3.2836x; 1.2159x over previous
//
#include <hip/hip_runtime.h>
#include <math.h>

// DifferentiableRAM: out[b,c,n,m] = gamma[b] * sum_h Fy[b,n,h] * sum_w x[b,c,h,w] * Fx[b,m,w]
// Reordered: G[bc][m][h] = (x[bc] @ Fx[b]^T)^T   (contraction over w, x native layout)
//            out[bc][n][m] = gamma * Fy[b] @ G[bc]^T (contraction over h, both k-contig)
// ws: Fx_b 8MB | Fy_b 8MB | G 25.2MB => 41.2 MB

namespace {

typedef __attribute__((ext_vector_type(8))) short v8s;    // 8 bf16
typedef __attribute__((ext_vector_type(4))) short v4s;    // 4 bf16 (8B)
typedef __attribute__((ext_vector_type(4))) float f32x4;  // MFMA C/D frag

constexpr int Bn = 32;
constexpr int Cc = 3;
constexpr int HW = 512;
constexpr int Nn = 256;
constexpr float SMALLF = 1e-4f;

__device__ inline unsigned short f2bf(float f) {
    union { float f; unsigned u; } v; v.f = f;
    unsigned r = v.u + 0x7FFF + ((v.u >> 16) & 1);   // RNE
    return (unsigned short)(r >> 16);
}

// ---------------- Kernel 1: Gaussian filterbanks (bf16 out) ---------------
__global__ __launch_bounds__(256) void fb_kernel(const float* __restrict__ p,
                                                 unsigned short* __restrict__ Fx,
                                                 unsigned short* __restrict__ Fy) {
    const int wid  = threadIdx.x >> 6;
    const int lane = threadIdx.x & 63;
    const int rid  = blockIdx.x * 4 + wid;        // 0..16383
    const int which = rid >> 13;
    const int r = rid & 8191;
    const int b = r >> 8;
    const int n = r & 255;

    const float* pb = p + b * 5;
    const float sigma2 = expf(pb[2]);
    const float delta  = expf(pb[3]) * (511.0f / 255.0f);
    const float g = (which == 0) ? (HW * (pb[0] + 1.0f) * 0.5f)
                                 : (HW * (pb[1] + 1.0f) * 0.5f);
    const float mu = g + delta * ((float)n - 128.5f);
    const float inv2s = 0.5f / sigma2;

    float f[8];
    float sum = 0.0f;
#pragma unroll
    for (int q = 0; q < 8; ++q) {
        float a = (float)(q * 64 + lane);
        float d = a - mu;
        f[q] = expf(-d * d * inv2s);
        sum += f[q];
    }
#pragma unroll
    for (int s = 1; s < 64; s <<= 1) sum += __shfl_xor(sum, s, 64);
    const float inv = 1.0f / (sum + SMALLF);

    unsigned short* dst = ((which == 0) ? Fx : Fy) + ((size_t)(b * Nn + n)) * HW;
#pragma unroll
    for (int q = 0; q < 8; ++q) dst[q * 64 + lane] = f2bf(f[q] * inv);
}

// ---------------- LDS helpers (XOR-swizzled, st_16x32-style) ---------------
// byte(row, kbyte) = row*128 + (kbyte ^ ((row&7)<<4)); tile = rows x 64 bf16.
__device__ inline v8s frag_read(const unsigned short* __restrict__ lds, int row, int kk, int lk) {
    int byte = row * 128 + (((kk * 64) + lk * 16) ^ ((row & 7) << 4));
    return *(const v8s*)((const char*)lds + byte);
}

// ---------------- Kernel 2: G[bc][m][h] = (x[bc] @ Fx_b[b]^T)^T ------------
// M=h (tile 128), N=m (tile 256 = full), K=w (512). 512 threads, 8 waves (2x4).
__global__ __launch_bounds__(512) void gemm1_kernel(const float* __restrict__ x,
                                                    const unsigned short* __restrict__ Fx_b,
                                                    unsigned short* __restrict__ G) {
    __shared__ unsigned short As[128 * 64];   // h rows, bf16 (converted)
    __shared__ unsigned short Bs[256 * 64];   // m rows
    const int t = threadIdx.x;
    const int bc = blockIdx.y, b = bc / 3;
    const int h0 = blockIdx.x * 128;

    const float* Ag = x + (size_t)bc * HW * HW + (size_t)h0 * HW;
    const unsigned short* Bg = Fx_b + (size_t)b * Nn * HW;

    const int wid = t >> 6, lane = t & 63, lr = lane & 15, lk = lane >> 4;
    const int wm = (wid >> 2) * 64;   // h-offset within 128
    const int wn = (wid & 3) * 64;    // m-offset within 256

    f32x4 acc[4][4];
#pragma unroll
    for (int i = 0; i < 4; ++i)
#pragma unroll
        for (int j = 0; j < 4; ++j) acc[i][j] = (f32x4){0.f, 0.f, 0.f, 0.f};

    const int oct = t & 7;          // k-octet (8 bf16)
    const int rowb = t >> 3;        // 0..63

    for (int k0 = 0; k0 < HW; k0 += 64) {
        __syncthreads();
        // stage A: 128 rows x 64 k, fp32 -> bf16
#pragma unroll
        for (int rb = 0; rb < 2; ++rb) {
            int row = rowb + 64 * rb;
            const float* s = Ag + (size_t)row * HW + k0 + oct * 8;
            float4 v0 = *(const float4*)s;
            float4 v1 = *(const float4*)(s + 4);
            unsigned short q[8] = {f2bf(v0.x), f2bf(v0.y), f2bf(v0.z), f2bf(v0.w),
                                   f2bf(v1.x), f2bf(v1.y), f2bf(v1.z), f2bf(v1.w)};
            int byte = row * 128 + ((oct * 16) ^ ((row & 7) << 4));
            *(v8s*)((char*)As + byte) = *(const v8s*)q;
        }
        // stage B: 256 rows x 64 k bf16
#pragma unroll
        for (int rb = 0; rb < 4; ++rb) {
            int row = rowb + 64 * rb;
            v8s v = *(const v8s*)(Bg + (size_t)row * HW + k0 + oct * 8);
            int byte = row * 128 + ((oct * 16) ^ ((row & 7) << 4));
            *(v8s*)((char*)Bs + byte) = v;
        }
        __syncthreads();
#pragma unroll
        for (int kk = 0; kk < 2; ++kk) {
            v8s af[4], bf[4];
#pragma unroll
            for (int mi = 0; mi < 4; ++mi) af[mi] = frag_read(As, wm + mi * 16 + lr, kk, lk);
#pragma unroll
            for (int ni = 0; ni < 4; ++ni) bf[ni] = frag_read(Bs, wn + ni * 16 + lr, kk, lk);
#pragma unroll
            for (int mi = 0; mi < 4; ++mi)
#pragma unroll
                for (int ni = 0; ni < 4; ++ni)
                    acc[mi][ni] = __builtin_amdgcn_mfma_f32_16x16x32_bf16(af[mi], bf[ni], acc[mi][ni], 0, 0, 0);
        }
    }

    // transposed store: G[m][h], each lane's 4 regs are 4 consecutive h -> 8B store
    unsigned short* Cg = G + (size_t)bc * Nn * HW;
#pragma unroll
    for (int mi = 0; mi < 4; ++mi)
#pragma unroll
        for (int ni = 0; ni < 4; ++ni) {
            int mg = wn + ni * 16 + lr;
            int hg = h0 + wm + mi * 16 + lk * 4;
            unsigned short q[4] = {f2bf(acc[mi][ni][0]), f2bf(acc[mi][ni][1]),
                                   f2bf(acc[mi][ni][2]), f2bf(acc[mi][ni][3])};
            *(v4s*)(Cg + (size_t)mg * HW + hg) = *(const v4s*)q;
        }
}

// ---------------- Kernel 3: out[bc][n][m] = gamma * Fy_b[b] @ G[bc]^T ------
// M=n, N=m (tiles 128x128), K=h (512). 256 threads, 4 waves (2x2).
__global__ __launch_bounds__(256) void gemm2_kernel(const unsigned short* __restrict__ Fy_b,
                                                    const unsigned short* __restrict__ G,
                                                    const float* __restrict__ p,
                                                    float* __restrict__ out) {
    __shared__ unsigned short As[128 * 64];
    __shared__ unsigned short Bs[128 * 64];
    const int t = threadIdx.x;
    const int bc = blockIdx.z, b = bc / 3;
    const int m0 = blockIdx.x * 128;
    const int n0 = blockIdx.y * 128;

    const unsigned short* Ag = Fy_b + (size_t)b * Nn * HW + (size_t)n0 * HW;
    const unsigned short* Bg = G + (size_t)bc * Nn * HW + (size_t)m0 * HW;
    const float gamma = expf(p[b * 5 + 4]);

    const int wid = t >> 6, lane = t & 63, lr = lane & 15, lk = lane >> 4;
    const int wm = (wid >> 1) * 64, wn = (wid & 1) * 64;

    f32x4 acc[4][4];
#pragma unroll
    for (int i = 0; i < 4; ++i)
#pragma unroll
        for (int j = 0; j < 4; ++j) acc[i][j] = (f32x4){0.f, 0.f, 0.f, 0.f};

    const int oct = t & 7;
    const int rowb = t >> 3;   // 0..31

    for (int k0 = 0; k0 < HW; k0 += 64) {
        __syncthreads();
#pragma unroll
        for (int rb = 0; rb < 4; ++rb) {
            int row = rowb + 32 * rb;
            v8s va = *(const v8s*)(Ag + (size_t)row * HW + k0 + oct * 8);
            v8s vb = *(const v8s*)(Bg + (size_t)row * HW + k0 + oct * 8);
            int byte = row * 128 + ((oct * 16) ^ ((row & 7) << 4));
            *(v8s*)((char*)As + byte) = va;
            *(v8s*)((char*)Bs + byte) = vb;
        }
        __syncthreads();
#pragma unroll
        for (int kk = 0; kk < 2; ++kk) {
            v8s af[4], bf[4];
#pragma unroll
            for (int mi = 0; mi < 4; ++mi) af[mi] = frag_read(As, wm + mi * 16 + lr, kk, lk);
#pragma unroll
            for (int ni = 0; ni < 4; ++ni) bf[ni] = frag_read(Bs, wn + ni * 16 + lr, kk, lk);
#pragma unroll
            for (int mi = 0; mi < 4; ++mi)
#pragma unroll
                for (int ni = 0; ni < 4; ++ni)
                    acc[mi][ni] = __builtin_amdgcn_mfma_f32_16x16x32_bf16(af[mi], bf[ni], acc[mi][ni], 0, 0, 0);
        }
    }

    float* Cg = out + (size_t)bc * Nn * Nn + (size_t)(n0 + wm) * Nn + (m0 + wn);
#pragma unroll
    for (int mi = 0; mi < 4; ++mi)
#pragma unroll
        for (int r = 0; r < 4; ++r) {
            int row = mi * 16 + lk * 4 + r;
#pragma unroll
            for (int ni = 0; ni < 4; ++ni)
                Cg[(size_t)row * Nn + ni * 16 + lr] = gamma * acc[mi][ni][r];
        }
}

} // anonymous namespace

extern "C" void kernel_launch(void* const* d_in, const int* in_sizes, int n_in,
                              void* d_out, int out_size, void* d_ws, size_t ws_size,
                              hipStream_t stream) {
    const float* x = (const float*)d_in[0];   // [32,3,512,512]
    const float* p = (const float*)d_in[1];   // [32,5]
    float* out = (float*)d_out;               // [32,3,256,256] f32

    char* ws = (char*)d_ws;
    unsigned short* Fx_b = (unsigned short*)ws;                    // 32*256*512
    unsigned short* Fy_b = Fx_b + (size_t)Bn * Nn * HW;            // 32*256*512
    unsigned short* G    = Fy_b + (size_t)Bn * Nn * HW;            // 96*256*512 (layout [bc][m][h])

    hipLaunchKernelGGL(fb_kernel, dim3(4096), dim3(256), 0, stream, p, Fx_b, Fy_b);
    hipLaunchKernelGGL(gemm1_kernel, dim3(4, Bn * Cc), dim3(512), 0, stream, x, Fx_b, G);
    hipLaunchKernelGGL(gemm2_kernel, dim3(2, 2, Bn * Cc), dim3(256), 0, stream, Fy_b, G, p, out);
}

// Round 7
// 68.545 us; speedup vs baseline: 3.3912x; 1.0328x over previous
//
#include <hip/hip_runtime.h>
#include <math.h>

// DifferentiableRAM: out[b,c,n,m] = gamma[b] * sum_h Fy[b,n,h] * sum_w x[b,c,h,w] * Fx[b,m,w]
// Reordered: G[bc][m][h] = (x[bc] @ Fx[b]^T)^T   (contraction over w, x native layout)
//            out[bc][n][m] = gamma * Fy[b] @ G[bc]^T (contraction over h, both k-contig)
// R6: gemm1 -> 256 thr / 128x128 tile (3 blocks/CU vs 1), XCD-swizzled 1D grids.
// ws: Fx_b 8MB | Fy_b 8MB | G 25.2MB => 41.2 MB

namespace {

typedef __attribute__((ext_vector_type(8))) short v8s;    // 8 bf16
typedef __attribute__((ext_vector_type(4))) short v4s;    // 4 bf16 (8B)
typedef __attribute__((ext_vector_type(4))) float f32x4;  // MFMA C/D frag

constexpr int Bn = 32;
constexpr int Cc = 3;
constexpr int HW = 512;
constexpr int Nn = 256;
constexpr float SMALLF = 1e-4f;

__device__ inline unsigned short f2bf(float f) {
    union { float f; unsigned u; } v; v.f = f;
    unsigned r = v.u + 0x7FFF + ((v.u >> 16) & 1);   // RNE
    return (unsigned short)(r >> 16);
}

// bijective XCD swizzle (grid % 8 == 0): consecutive logical wgs share an XCD's L2
__device__ inline int xcd_swz(int bid, int nwg) {
    return (bid & 7) * (nwg >> 3) + (bid >> 3);
}

// ---------------- Kernel 1: Gaussian filterbanks (bf16 out) ---------------
__global__ __launch_bounds__(256) void fb_kernel(const float* __restrict__ p,
                                                 unsigned short* __restrict__ Fx,
                                                 unsigned short* __restrict__ Fy) {
    const int wid  = threadIdx.x >> 6;
    const int lane = threadIdx.x & 63;
    const int rid  = blockIdx.x * 4 + wid;        // 0..16383
    const int which = rid >> 13;
    const int r = rid & 8191;
    const int b = r >> 8;
    const int n = r & 255;

    const float* pb = p + b * 5;
    const float sigma2 = expf(pb[2]);
    const float delta  = expf(pb[3]) * (511.0f / 255.0f);
    const float g = (which == 0) ? (HW * (pb[0] + 1.0f) * 0.5f)
                                 : (HW * (pb[1] + 1.0f) * 0.5f);
    const float mu = g + delta * ((float)n - 128.5f);
    const float inv2s = 0.5f / sigma2;

    float f[8];
    float sum = 0.0f;
#pragma unroll
    for (int q = 0; q < 8; ++q) {
        float a = (float)(q * 64 + lane);
        float d = a - mu;
        f[q] = expf(-d * d * inv2s);
        sum += f[q];
    }
#pragma unroll
    for (int s = 1; s < 64; s <<= 1) sum += __shfl_xor(sum, s, 64);
    const float inv = 1.0f / (sum + SMALLF);

    unsigned short* dst = ((which == 0) ? Fx : Fy) + ((size_t)(b * Nn + n)) * HW;
#pragma unroll
    for (int q = 0; q < 8; ++q) dst[q * 64 + lane] = f2bf(f[q] * inv);
}

// ---------------- LDS helpers (XOR-swizzled) -------------------------------
// byte(row, kbyte) = row*128 + (kbyte ^ ((row&7)<<4)); tile = rows x 64 bf16.
__device__ inline v8s frag_read(const unsigned short* __restrict__ lds, int row, int kk, int lk) {
    int byte = row * 128 + (((kk * 64) + lk * 16) ^ ((row & 7) << 4));
    return *(const v8s*)((const char*)lds + byte);
}

// ---------------- Kernel 2: G[bc][m][h] = (x[bc] @ Fx_b[b]^T)^T ------------
// M=h (tile 128), N=m (tile 128), K=w (512). 256 threads, 4 waves (2x2).
// grid = 768 (1D, XCD-swizzled): wg -> bc*8 + htile*2 + mtile
__global__ __launch_bounds__(256, 3) void gemm1_kernel(const float* __restrict__ x,
                                                       const unsigned short* __restrict__ Fx_b,
                                                       unsigned short* __restrict__ G) {
    __shared__ unsigned short As[128 * 64];   // h rows, bf16 (converted)
    __shared__ unsigned short Bs[128 * 64];   // m rows
    const int t = threadIdx.x;
    const int wg = xcd_swz(blockIdx.x, 768);
    const int bc = wg >> 3, b = bc / 3;
    const int rem = wg & 7;
    const int h0 = (rem >> 1) * 128;
    const int m0 = (rem & 1) * 128;

    const float* Ag = x + (size_t)bc * HW * HW + (size_t)h0 * HW;
    const unsigned short* Bg = Fx_b + (size_t)b * Nn * HW + (size_t)m0 * HW;

    const int wid = t >> 6, lane = t & 63, lr = lane & 15, lk = lane >> 4;
    const int wm = (wid >> 1) * 64;   // h-offset within 128
    const int wn = (wid & 1) * 64;    // m-offset within 128

    f32x4 acc[4][4];
#pragma unroll
    for (int i = 0; i < 4; ++i)
#pragma unroll
        for (int j = 0; j < 4; ++j) acc[i][j] = (f32x4){0.f, 0.f, 0.f, 0.f};

    const int oct = t & 7;          // k-octet (8 bf16)
    const int rowb = t >> 3;        // 0..31

    for (int k0 = 0; k0 < HW; k0 += 64) {
        __syncthreads();
        // stage A: 128 rows x 64 k, fp32 -> bf16
#pragma unroll
        for (int rb = 0; rb < 4; ++rb) {
            int row = rowb + 32 * rb;
            const float* s = Ag + (size_t)row * HW + k0 + oct * 8;
            float4 v0 = *(const float4*)s;
            float4 v1 = *(const float4*)(s + 4);
            unsigned short q[8] = {f2bf(v0.x), f2bf(v0.y), f2bf(v0.z), f2bf(v0.w),
                                   f2bf(v1.x), f2bf(v1.y), f2bf(v1.z), f2bf(v1.w)};
            int byte = row * 128 + ((oct * 16) ^ ((row & 7) << 4));
            *(v8s*)((char*)As + byte) = *(const v8s*)q;
        }
        // stage B: 128 rows x 64 k bf16
#pragma unroll
        for (int rb = 0; rb < 4; ++rb) {
            int row = rowb + 32 * rb;
            v8s v = *(const v8s*)(Bg + (size_t)row * HW + k0 + oct * 8);
            int byte = row * 128 + ((oct * 16) ^ ((row & 7) << 4));
            *(v8s*)((char*)Bs + byte) = v;
        }
        __syncthreads();
#pragma unroll
        for (int kk = 0; kk < 2; ++kk) {
            v8s af[4], bf[4];
#pragma unroll
            for (int mi = 0; mi < 4; ++mi) af[mi] = frag_read(As, wm + mi * 16 + lr, kk, lk);
#pragma unroll
            for (int ni = 0; ni < 4; ++ni) bf[ni] = frag_read(Bs, wn + ni * 16 + lr, kk, lk);
#pragma unroll
            for (int mi = 0; mi < 4; ++mi)
#pragma unroll
                for (int ni = 0; ni < 4; ++ni)
                    acc[mi][ni] = __builtin_amdgcn_mfma_f32_16x16x32_bf16(af[mi], bf[ni], acc[mi][ni], 0, 0, 0);
        }
    }

    // transposed store: G[m][h], each lane's 4 acc regs = 4 consecutive h -> 8B store
    unsigned short* Cg = G + (size_t)bc * Nn * HW;
#pragma unroll
    for (int mi = 0; mi < 4; ++mi)
#pragma unroll
        for (int ni = 0; ni < 4; ++ni) {
            int mg = m0 + wn + ni * 16 + lr;
            int hg = h0 + wm + mi * 16 + lk * 4;
            unsigned short q[4] = {f2bf(acc[mi][ni][0]), f2bf(acc[mi][ni][1]),
                                   f2bf(acc[mi][ni][2]), f2bf(acc[mi][ni][3])};
            *(v4s*)(Cg + (size_t)mg * HW + hg) = *(const v4s*)q;
        }
}

// ---------------- Kernel 3: out[bc][n][m] = gamma * Fy_b[b] @ G[bc]^T ------
// M=n, N=m (tiles 128x128), K=h (512). 256 threads, 4 waves (2x2).
// grid = 384 (1D, XCD-swizzled): wg -> bc*4 + mtile*2 + ntile
__global__ __launch_bounds__(256, 3) void gemm2_kernel(const unsigned short* __restrict__ Fy_b,
                                                       const unsigned short* __restrict__ G,
                                                       const float* __restrict__ p,
                                                       float* __restrict__ out) {
    __shared__ unsigned short As[128 * 64];
    __shared__ unsigned short Bs[128 * 64];
    const int t = threadIdx.x;
    const int wg = xcd_swz(blockIdx.x, 384);
    const int bc = wg >> 2, b = bc / 3;
    const int rem = wg & 3;
    const int m0 = (rem >> 1) * 128;
    const int n0 = (rem & 1) * 128;

    const unsigned short* Ag = Fy_b + (size_t)b * Nn * HW + (size_t)n0 * HW;
    const unsigned short* Bg = G + (size_t)bc * Nn * HW + (size_t)m0 * HW;
    const float gamma = expf(p[b * 5 + 4]);

    const int wid = t >> 6, lane = t & 63, lr = lane & 15, lk = lane >> 4;
    const int wm = (wid >> 1) * 64, wn = (wid & 1) * 64;

    f32x4 acc[4][4];
#pragma unroll
    for (int i = 0; i < 4; ++i)
#pragma unroll
        for (int j = 0; j < 4; ++j) acc[i][j] = (f32x4){0.f, 0.f, 0.f, 0.f};

    const int oct = t & 7;
    const int rowb = t >> 3;   // 0..31

    for (int k0 = 0; k0 < HW; k0 += 64) {
        __syncthreads();
#pragma unroll
        for (int rb = 0; rb < 4; ++rb) {
            int row = rowb + 32 * rb;
            v8s va = *(const v8s*)(Ag + (size_t)row * HW + k0 + oct * 8);
            v8s vb = *(const v8s*)(Bg + (size_t)row * HW + k0 + oct * 8);
            int byte = row * 128 + ((oct * 16) ^ ((row & 7) << 4));
            *(v8s*)((char*)As + byte) = va;
            *(v8s*)((char*)Bs + byte) = vb;
        }
        __syncthreads();
#pragma unroll
        for (int kk = 0; kk < 2; ++kk) {
            v8s af[4], bf[4];
#pragma unroll
            for (int mi = 0; mi < 4; ++mi) af[mi] = frag_read(As, wm + mi * 16 + lr, kk, lk);
#pragma unroll
            for (int ni = 0; ni < 4; ++ni) bf[ni] = frag_read(Bs, wn + ni * 16 + lr, kk, lk);
#pragma unroll
            for (int mi = 0; mi < 4; ++mi)
#pragma unroll
                for (int ni = 0; ni < 4; ++ni)
                    acc[mi][ni] = __builtin_amdgcn_mfma_f32_16x16x32_bf16(af[mi], bf[ni], acc[mi][ni], 0, 0, 0);
        }
    }

    float* Cg = out + (size_t)bc * Nn * Nn + (size_t)(n0 + wm) * Nn + (m0 + wn);
#pragma unroll
    for (int mi = 0; mi < 4; ++mi)
#pragma unroll
        for (int r = 0; r < 4; ++r) {
            int row = mi * 16 + lk * 4 + r;
#pragma unroll
            for (int ni = 0; ni < 4; ++ni)
                Cg[(size_t)row * Nn + ni * 16 + lr] = gamma * acc[mi][ni][r];
        }
}

} // anonymous namespace

extern "C" void kernel_launch(void* const* d_in, const int* in_sizes, int n_in,
                              void* d_out, int out_size, void* d_ws, size_t ws_size,
                              hipStream_t stream) {
    const float* x = (const float*)d_in[0];   // [32,3,512,512]
    const float* p = (const float*)d_in[1];   // [32,5]
    float* out = (float*)d_out;               // [32,3,256,256] f32

    char* ws = (char*)d_ws;
    unsigned short* Fx_b = (unsigned short*)ws;                    // 32*256*512
    unsigned short* Fy_b = Fx_b + (size_t)Bn * Nn * HW;            // 32*256*512
    unsigned short* G    = Fy_b + (size_t)Bn * Nn * HW;            // 96*256*512 (layout [bc][m][h])

    hipLaunchKernelGGL(fb_kernel, dim3(4096), dim3(256), 0, stream, p, Fx_b, Fy_b);
    hipLaunchKernelGGL(gemm1_kernel, dim3(768), dim3(256), 0, stream, x, Fx_b, G);
    hipLaunchKernelGGL(gemm2_kernel, dim3(384), dim3(256), 0, stream, Fy_b, G, p, out);
}

// Round 8
// 63.075 us; speedup vs baseline: 3.6853x; 1.0867x over previous
//
#include <hip/hip_runtime.h>
#include <hip/hip_bf16.h>
#include <math.h>

// DifferentiableRAM: out[b,c,n,m] = gamma[b] * sum_h Fy[b,n,h] * sum_w x[b,c,h,w] * Fx[b,m,w]
// G[bc][m][h] = (x[bc] @ Fx[b]^T)^T ; out[bc][n][m] = gamma * Fy[b] @ G[bc]^T
// R8: gemm1 128h x 256m tile (x read once), register k-prefetch (T14) in both
//     GEMMs so HBM latency hides under MFMA; HW bf16 cvt instead of bit-twiddle.
// ws: Fx_b 8MB | Fy_b 8MB | G 25.2MB => 41.2 MB

namespace {

typedef __attribute__((ext_vector_type(8))) short v8s;    // 8 bf16
typedef __attribute__((ext_vector_type(4))) short v4s;    // 4 bf16 (8B)
typedef __attribute__((ext_vector_type(4))) float f32x4;  // MFMA C/D frag

constexpr int Bn = 32;
constexpr int Cc = 3;
constexpr int HW = 512;
constexpr int Nn = 256;
constexpr float SMALLF = 1e-4f;

__device__ inline unsigned short f2bf(float f) {
    __hip_bfloat16 h = __float2bfloat16(f);   // HW RNE cvt (compiler emits v_cvt)
    union { __hip_bfloat16 h; unsigned short u; } c;
    c.h = h;
    return c.u;
}

// bijective XCD swizzle (grid % 8 == 0)
__device__ inline int xcd_swz(int bid, int nwg) {
    return (bid & 7) * (nwg >> 3) + (bid >> 3);
}

// ---------------- Kernel 1: Gaussian filterbanks (bf16 out) ---------------
__global__ __launch_bounds__(256) void fb_kernel(const float* __restrict__ p,
                                                 unsigned short* __restrict__ Fx,
                                                 unsigned short* __restrict__ Fy) {
    const int wid  = threadIdx.x >> 6;
    const int lane = threadIdx.x & 63;
    const int rid  = blockIdx.x * 4 + wid;        // 0..16383
    const int which = rid >> 13;
    const int r = rid & 8191;
    const int b = r >> 8;
    const int n = r & 255;

    const float* pb = p + b * 5;
    const float sigma2 = expf(pb[2]);
    const float delta  = expf(pb[3]) * (511.0f / 255.0f);
    const float g = (which == 0) ? (HW * (pb[0] + 1.0f) * 0.5f)
                                 : (HW * (pb[1] + 1.0f) * 0.5f);
    const float mu = g + delta * ((float)n - 128.5f);
    const float inv2s = 0.5f / sigma2;

    float f[8];
    float sum = 0.0f;
#pragma unroll
    for (int q = 0; q < 8; ++q) {
        float a = (float)(q * 64 + lane);
        float d = a - mu;
        f[q] = expf(-d * d * inv2s);
        sum += f[q];
    }
#pragma unroll
    for (int s = 1; s < 64; s <<= 1) sum += __shfl_xor(sum, s, 64);
    const float inv = 1.0f / (sum + SMALLF);

    unsigned short* dst = ((which == 0) ? Fx : Fy) + ((size_t)(b * Nn + n)) * HW;
#pragma unroll
    for (int q = 0; q < 8; ++q) dst[q * 64 + lane] = f2bf(f[q] * inv);
}

// ---------------- LDS helpers (XOR-swizzled) -------------------------------
// byte(row, kbyte) = row*128 + (kbyte ^ ((row&7)<<4)); tile = rows x 64 bf16.
__device__ inline v8s frag_read(const unsigned short* __restrict__ lds, int row, int kk, int lk) {
    int byte = row * 128 + (((kk * 64) + lk * 16) ^ ((row & 7) << 4));
    return *(const v8s*)((const char*)lds + byte);
}

// ---------------- Kernel 2: G[bc][m][h] = (x[bc] @ Fx_b[b]^T)^T ------------
// M=h (tile 128), N=m (tile 256 = full), K=w (512). 512 thr, 8 waves (2h x 4m).
// x read exactly once. Register k-prefetch: LOAD(k+1) issued before COMPUTE(k).
// grid = 384 (1D, XCD-swizzled): wg -> bc*4 + htile
__global__ __launch_bounds__(512, 2) void gemm1_kernel(const float* __restrict__ x,
                                                       const unsigned short* __restrict__ Fx_b,
                                                       unsigned short* __restrict__ G) {
    __shared__ unsigned short As[128 * 64];   // h rows (converted bf16)
    __shared__ unsigned short Bs[256 * 64];   // m rows
    const int t = threadIdx.x;
    const int wg = xcd_swz(blockIdx.x, 384);
    const int bc = wg >> 2, b = bc / 3;
    const int h0 = (wg & 3) * 128;

    const float* Ag = x + (size_t)bc * HW * HW + (size_t)h0 * HW;
    const unsigned short* Bg = Fx_b + (size_t)b * Nn * HW;

    const int wid = t >> 6, lane = t & 63, lr = lane & 15, lk = lane >> 4;
    const int wm = (wid >> 2) * 64;   // h-offset within 128
    const int wn = (wid & 3) * 64;    // m-offset within 256

    const int oct = t & 7;            // k-octet (8 elems)
    const int rowb = t >> 3;          // 0..63

    f32x4 acc[4][4];
#pragma unroll
    for (int i = 0; i < 4; ++i)
#pragma unroll
        for (int j = 0; j < 4; ++j) acc[i][j] = (f32x4){0.f, 0.f, 0.f, 0.f};

    // staged registers (held across the compute phase)
    float4 xa[2][2];   // A: 2 rows x 8 floats
    v8s    fxv[4];     // B: 4 rows x 8 bf16

#define G1_LOAD(K0)                                                              \
    {                                                                            \
        _Pragma("unroll")                                                        \
        for (int rb = 0; rb < 2; ++rb) {                                         \
            const float* s_ = Ag + (size_t)(rowb + 64 * rb) * HW + (K0) + oct * 8; \
            xa[rb][0] = *(const float4*)s_;                                      \
            xa[rb][1] = *(const float4*)(s_ + 4);                                \
        }                                                                        \
        _Pragma("unroll")                                                        \
        for (int rb = 0; rb < 4; ++rb)                                           \
            fxv[rb] = *(const v8s*)(Bg + (size_t)(rowb + 64 * rb) * HW + (K0) + oct * 8); \
    }

#define G1_WRITE()                                                               \
    {                                                                            \
        _Pragma("unroll")                                                        \
        for (int rb = 0; rb < 2; ++rb) {                                         \
            int row = rowb + 64 * rb;                                            \
            unsigned short q_[8] = {f2bf(xa[rb][0].x), f2bf(xa[rb][0].y),        \
                                    f2bf(xa[rb][0].z), f2bf(xa[rb][0].w),        \
                                    f2bf(xa[rb][1].x), f2bf(xa[rb][1].y),        \
                                    f2bf(xa[rb][1].z), f2bf(xa[rb][1].w)};       \
            int byte = row * 128 + ((oct * 16) ^ ((row & 7) << 4));              \
            *(v8s*)((char*)As + byte) = *(const v8s*)q_;                         \
        }                                                                        \
        _Pragma("unroll")                                                        \
        for (int rb = 0; rb < 4; ++rb) {                                         \
            int row = rowb + 64 * rb;                                            \
            int byte = row * 128 + ((oct * 16) ^ ((row & 7) << 4));              \
            *(v8s*)((char*)Bs + byte) = fxv[rb];                                 \
        }                                                                        \
    }

    G1_LOAD(0);
#pragma unroll 1
    for (int ks = 0; ks < 8; ++ks) {
        __syncthreads();            // previous compute done reading LDS
        G1_WRITE();                 // waits vmcnt for staged regs, converts, writes
        __syncthreads();
        if (ks < 7) G1_LOAD((ks + 1) * 64);   // in flight during compute below
#pragma unroll
        for (int kk = 0; kk < 2; ++kk) {
            v8s af[4], bf[4];
#pragma unroll
            for (int mi = 0; mi < 4; ++mi) af[mi] = frag_read(As, wm + mi * 16 + lr, kk, lk);
#pragma unroll
            for (int ni = 0; ni < 4; ++ni) bf[ni] = frag_read(Bs, wn + ni * 16 + lr, kk, lk);
#pragma unroll
            for (int mi = 0; mi < 4; ++mi)
#pragma unroll
                for (int ni = 0; ni < 4; ++ni)
                    acc[mi][ni] = __builtin_amdgcn_mfma_f32_16x16x32_bf16(af[mi], bf[ni], acc[mi][ni], 0, 0, 0);
        }
    }
#undef G1_LOAD
#undef G1_WRITE

    // transposed store: G[m][h]; lane's 4 acc regs = 4 consecutive h -> 8B store
    unsigned short* Cg = G + (size_t)bc * Nn * HW;
#pragma unroll
    for (int mi = 0; mi < 4; ++mi)
#pragma unroll
        for (int ni = 0; ni < 4; ++ni) {
            int mg = wn + ni * 16 + lr;
            int hg = h0 + wm + mi * 16 + lk * 4;
            unsigned short q[4] = {f2bf(acc[mi][ni][0]), f2bf(acc[mi][ni][1]),
                                   f2bf(acc[mi][ni][2]), f2bf(acc[mi][ni][3])};
            *(v4s*)(Cg + (size_t)mg * HW + hg) = *(const v4s*)q;
        }
}

// ---------------- Kernel 3: out[bc][n][m] = gamma * Fy_b[b] @ G[bc]^T ------
// M=n, N=m (tiles 128x128), K=h (512). 256 thr, 4 waves (2x2), reg k-prefetch.
// grid = 384 (1D, XCD-swizzled): wg -> bc*4 + mtile*2 + ntile
__global__ __launch_bounds__(256, 2) void gemm2_kernel(const unsigned short* __restrict__ Fy_b,
                                                       const unsigned short* __restrict__ G,
                                                       const float* __restrict__ p,
                                                       float* __restrict__ out) {
    __shared__ unsigned short As[128 * 64];
    __shared__ unsigned short Bs[128 * 64];
    const int t = threadIdx.x;
    const int wg = xcd_swz(blockIdx.x, 384);
    const int bc = wg >> 2, b = bc / 3;
    const int rem = wg & 3;
    const int m0 = (rem >> 1) * 128;
    const int n0 = (rem & 1) * 128;

    const unsigned short* Ag = Fy_b + (size_t)b * Nn * HW + (size_t)n0 * HW;
    const unsigned short* Bg = G + (size_t)bc * Nn * HW + (size_t)m0 * HW;
    const float gamma = expf(p[b * 5 + 4]);

    const int wid = t >> 6, lane = t & 63, lr = lane & 15, lk = lane >> 4;
    const int wm = (wid >> 1) * 64, wn = (wid & 1) * 64;

    const int oct = t & 7;
    const int rowb = t >> 3;   // 0..31

    f32x4 acc[4][4];
#pragma unroll
    for (int i = 0; i < 4; ++i)
#pragma unroll
        for (int j = 0; j < 4; ++j) acc[i][j] = (f32x4){0.f, 0.f, 0.f, 0.f};

    v8s va[4], vb[4];

#define G2_LOAD(K0)                                                              \
    {                                                                            \
        _Pragma("unroll")                                                        \
        for (int rb = 0; rb < 4; ++rb) {                                         \
            int row = rowb + 32 * rb;                                            \
            va[rb] = *(const v8s*)(Ag + (size_t)row * HW + (K0) + oct * 8);      \
            vb[rb] = *(const v8s*)(Bg + (size_t)row * HW + (K0) + oct * 8);      \
        }                                                                        \
    }

    G2_LOAD(0);
#pragma unroll 1
    for (int ks = 0; ks < 8; ++ks) {
        __syncthreads();
#pragma unroll
        for (int rb = 0; rb < 4; ++rb) {
            int row = rowb + 32 * rb;
            int byte = row * 128 + ((oct * 16) ^ ((row & 7) << 4));
            *(v8s*)((char*)As + byte) = va[rb];
            *(v8s*)((char*)Bs + byte) = vb[rb];
        }
        __syncthreads();
        if (ks < 7) G2_LOAD((ks + 1) * 64);
#pragma unroll
        for (int kk = 0; kk < 2; ++kk) {
            v8s af[4], bf[4];
#pragma unroll
            for (int mi = 0; mi < 4; ++mi) af[mi] = frag_read(As, wm + mi * 16 + lr, kk, lk);
#pragma unroll
            for (int ni = 0; ni < 4; ++ni) bf[ni] = frag_read(Bs, wn + ni * 16 + lr, kk, lk);
#pragma unroll
            for (int mi = 0; mi < 4; ++mi)
#pragma unroll
                for (int ni = 0; ni < 4; ++ni)
                    acc[mi][ni] = __builtin_amdgcn_mfma_f32_16x16x32_bf16(af[mi], bf[ni], acc[mi][ni], 0, 0, 0);
        }
    }
#undef G2_LOAD

    float* Cg = out + (size_t)bc * Nn * Nn + (size_t)(n0 + wm) * Nn + (m0 + wn);
#pragma unroll
    for (int mi = 0; mi < 4; ++mi)
#pragma unroll
        for (int r = 0; r < 4; ++r) {
            int row = mi * 16 + lk * 4 + r;
#pragma unroll
            for (int ni = 0; ni < 4; ++ni)
                Cg[(size_t)row * Nn + ni * 16 + lr] = gamma * acc[mi][ni][r];
        }
}

} // anonymous namespace

extern "C" void kernel_launch(void* const* d_in, const int* in_sizes, int n_in,
                              void* d_out, int out_size, void* d_ws, size_t ws_size,
                              hipStream_t stream) {
    const float* x = (const float*)d_in[0];   // [32,3,512,512]
    const float* p = (const float*)d_in[1];   // [32,5]
    float* out = (float*)d_out;               // [32,3,256,256] f32

    char* ws = (char*)d_ws;
    unsigned short* Fx_b = (unsigned short*)ws;                    // 32*256*512
    unsigned short* Fy_b = Fx_b + (size_t)Bn * Nn * HW;            // 32*256*512
    unsigned short* G    = Fy_b + (size_t)Bn * Nn * HW;            // 96*256*512 ([bc][m][h])

    hipLaunchKernelGGL(fb_kernel, dim3(4096), dim3(256), 0, stream, p, Fx_b, Fy_b);
    hipLaunchKernelGGL(gemm1_kernel, dim3(384), dim3(512), 0, stream, x, Fx_b, G);
    hipLaunchKernelGGL(gemm2_kernel, dim3(384), dim3(256), 0, stream, Fy_b, G, p, out);
}